// Round 28
// baseline (424.777 us; speedup 1.0000x reference)
//
#include <hip/hip_runtime.h>
#include <hip/hip_bf16.h>

#define NE 8
#define HD 256
#define NT 64
#define NTHREADS 512
#define WPITCH 32
#define SLICE_ELEMS (HD * WPITCH)      // 8192 elems = 16384 B per K-slice

typedef __attribute__((ext_vector_type(8))) short short8;
typedef __attribute__((ext_vector_type(4))) float f32x4;

__device__ __forceinline__ unsigned short f2bf_u16(float f) {
    union { __hip_bfloat16 b; unsigned short u; } v;
    v.b = __float2bfloat16(f);          // HW RNE convert
    return v.u;
}
__device__ __forceinline__ unsigned int pack2bf(float lo, float hi) {
    return (unsigned int)f2bf_u16(lo) | ((unsigned int)f2bf_u16(hi) << 16);
}
// hi/lo bf16 split: v ≈ hi + lo with |v - hi - lo| <= 2^-16 |v|.
__device__ __forceinline__ void bfsplit(float v, unsigned short& hi, unsigned short& lo) {
    hi = f2bf_u16(v);
    union { unsigned int u; float f; } c; c.u = ((unsigned int)hi) << 16;
    lo = f2bf_u16(v - c.f);
}
// Act LDS swizzle (element units), proven in R12/R17.
__device__ __forceinline__ int swz(int row, int col) {
    return row * HD + (col ^ ((row & 7) << 3));
}

// Weights pre-swizzled: Wp[e][slice s][n][32], [n][kk] = W[k=s*32+kk][n].
__global__ void prep_weights(const float* __restrict__ W1, const float* __restrict__ W2,
                             unsigned short* __restrict__ W1p, unsigned short* __restrict__ W2p) {
    int idx = blockIdx.x * blockDim.x + threadIdx.x;
    const int TOT = NE * 8 * SLICE_ELEMS;
    if (idx >= TOT) return;
    int kk = idx & 31;
    int n  = (idx >> 5) & 255;
    int s  = (idx >> 13) & 7;
    int e  = idx >> 16;
    int k = s * 32 + kk;
    W1p[idx] = f2bf_u16(W1[(e * HD + k) * HD + n]);
    W2p[idx] = f2bf_u16(W2[(e * HD + k) * HD + n]);
}

// Layer-0 as a K=32 MFMA slice (bias folded in; pairs with cbufK B-slots).
__global__ void prep_w0(const float* __restrict__ W0, const float* __restrict__ b0,
                        unsigned short* __restrict__ W0k) {
    int idx = blockIdx.x * blockDim.x + threadIdx.x;   // e*HD + n
    if (idx >= NE * HD) return;
    int n = idx & 255, e = idx >> 8;
    float wx = W0[(e*3+0)*HD + n], wy = W0[(e*3+1)*HD + n], wz = W0[(e*3+2)*HD + n];
    float bb = b0[e*HD + n];
    unsigned short xh,xl,yh,yl,zh,zl,bh,bl;
    bfsplit(wx,xh,xl); bfsplit(wy,yh,yl); bfsplit(wz,zh,zl); bfsplit(bb,bh,bl);
    unsigned short s[32] = {xh,xh,xl, yh,yh,yl, zh,zh,zl, bh,bl};  // rest zero
    unsigned short* dst = W0k + idx * 32;
    #pragma unroll
    for (int i = 0; i < 32; ++i) dst[i] = s[i];
}

// One K-slice: 4 af DIRECT FROM L2 (own neuron quarter; h-pair waves read the
// same lines -> L1 hits) x 2 bf (Act LDS, own 32-pt half) -> 8 MFMA.
// acc[4][2] = 32 regs -> total wave regs ~56-64 -> 8 waves/SIMD bin.
#define KSLICE_BODY(WSRC, K0)                                                                \
    {                                                                                        \
        const unsigned short* Ar = (WSRC) + (g*64 + l15) * WPITCH + kg*8;                    \
        short8 af0 = *(const short8*)(Ar + 0*16*WPITCH);                                     \
        short8 af1 = *(const short8*)(Ar + 1*16*WPITCH);                                     \
        short8 af2 = *(const short8*)(Ar + 2*16*WPITCH);                                     \
        short8 af3 = *(const short8*)(Ar + 3*16*WPITCH);                                     \
        const int k0 = (K0) + kg*8;                                                          \
        _Pragma("unroll")                                                                    \
        for (int nt = 0; nt < 2; ++nt) {                                                     \
            short8 bf = *(const short8*)(Act + swz(h*32 + nt*16 + l15, k0));                 \
            acc[0][nt] = __builtin_amdgcn_mfma_f32_16x16x32_bf16(af0, bf, acc[0][nt], 0,0,0);\
            acc[1][nt] = __builtin_amdgcn_mfma_f32_16x16x32_bf16(af1, bf, acc[1][nt], 0,0,0);\
            acc[2][nt] = __builtin_amdgcn_mfma_f32_16x16x32_bf16(af2, bf, acc[2][nt], 0,0,0);\
            acc[3][nt] = __builtin_amdgcn_mfma_f32_16x16x32_bf16(af3, bf, acc[3][nt], 0,0,0);\
        }                                                                                    \
    }

#define ACC_CLEAR()                                           \
    _Pragma("unroll")                                         \
    for (int mt = 0; mt < 4; ++mt)                            \
        _Pragma("unroll")                                     \
        for (int nt = 0; nt < 2; ++nt)                        \
            acc[mt][nt] = (f32x4){0.f, 0.f, 0.f, 0.f};

// One expert per block: blockIdx = tile*8 + e (XCD round-robin -> blocks on an
// XCD share the expert; weights L2-resident). 8 waves: wave (g=w>>1, h=w&1)
// owns neurons [g*64,+64) x points [h*32,+32). LDS 37888 B -> 4 blocks/CU;
// regs ~60/wave -> 8 waves/SIMD bin -> 32 waves/CU. K-loops barrier-free;
// 5 barriers/block. (512,4) pins the 64-VGPR bin (demand fits; R20 = 56).
__global__ __launch_bounds__(NTHREADS, 4) void moe_expert(
    const float* __restrict__ coords, int npts,
    const unsigned short* __restrict__ W0k, const float* __restrict__ b1,
    const unsigned short* __restrict__ W1p,
    const unsigned short* __restrict__ W2p, const float* __restrict__ b2,
    const float* __restrict__ W3, const float* __restrict__ b3,
    float* __restrict__ ws)
{
    __shared__ __align__(16) unsigned short Act[NT * HD];      // 32 KB
    __shared__ __align__(16) unsigned short cbufK[NT * 32];    // 4 KB
    __shared__ float pscr[NT * 4];                             // 1 KB

    const int t = threadIdx.x;
    const int lane = t & 63;
    const int w = t >> 6;       // 0..7
    const int g = w >> 1;       // 0..3: neuron group of 64
    const int h = w & 1;        // 0..1: point half of 32
    const int l15 = lane & 15;
    const int kg = lane >> 4;
    const int e = blockIdx.x & 7;
    const int p0 = (blockIdx.x >> 3) * NT;

    const unsigned short* W0e = W0k + e * SLICE_ELEMS;
    const unsigned short* W1e = W1p + e * 8 * SLICE_ELEMS;
    const unsigned short* W2e = W2p + e * 8 * SLICE_ELEMS;

    // ---- phase 0: build per-point L0 B-slots (hi/lo split) ----
    if (t < NT) {
        int p = p0 + t;
        int pc = p < npts ? p : npts - 1;      // clamp; store masked later
        float x = coords[pc*3], y = coords[pc*3+1], z = coords[pc*3+2];
        unsigned short xh,xl,yh,yl,zh,zl;
        bfsplit(x,xh,xl); bfsplit(y,yh,yl); bfsplit(z,zh,zl);
        const unsigned short ONE = 0x3F80;     // bf16(1.0)
        union { unsigned short s[32]; uint4 q[4]; } pk;
        #pragma unroll
        for (int i = 0; i < 32; ++i) pk.s[i] = 0;
        pk.s[0]=xh; pk.s[1]=xl; pk.s[2]=xh;
        pk.s[3]=yh; pk.s[4]=yl; pk.s[5]=yh;
        pk.s[6]=zh; pk.s[7]=zl; pk.s[8]=zh;
        pk.s[9]=ONE; pk.s[10]=ONE;
        uint4* dst = (uint4*)(cbufK + t * 32);
        dst[0]=pk.q[0]; dst[1]=pk.q[1]; dst[2]=pk.q[2]; dst[3]=pk.q[3];
    }
    f32x4 b1v[4];
    #pragma unroll
    for (int mt = 0; mt < 4; ++mt)
        b1v[mt] = *(const f32x4*)(b1 + e*HD + g*64 + mt*16 + kg*4);
    __syncthreads();                    // [1] cbufK visible

    f32x4 acc[4][2];
    ACC_CLEAR()

    // ---- phase 1: L0 as one MFMA K-slice (af from L2, bias in slots) ----
    {
        const unsigned short* Ar = W0e + (g*64 + l15) * WPITCH + kg*8;
        short8 af0 = *(const short8*)(Ar + 0*16*WPITCH);
        short8 af1 = *(const short8*)(Ar + 1*16*WPITCH);
        short8 af2 = *(const short8*)(Ar + 2*16*WPITCH);
        short8 af3 = *(const short8*)(Ar + 3*16*WPITCH);
        #pragma unroll
        for (int nt = 0; nt < 2; ++nt) {
            short8 bf = *(const short8*)(cbufK + (h*32 + nt*16 + l15) * 32 + kg*8);
            acc[0][nt] = __builtin_amdgcn_mfma_f32_16x16x32_bf16(af0, bf, acc[0][nt], 0,0,0);
            acc[1][nt] = __builtin_amdgcn_mfma_f32_16x16x32_bf16(af1, bf, acc[1][nt], 0,0,0);
            acc[2][nt] = __builtin_amdgcn_mfma_f32_16x16x32_bf16(af2, bf, acc[2][nt], 0,0,0);
            acc[3][nt] = __builtin_amdgcn_mfma_f32_16x16x32_bf16(af3, bf, acc[3][nt], 0,0,0);
        }
        // L0 epilogue: relu + pack -> Act (bias already in the MFMA slots)
        #pragma unroll
        for (int mt = 0; mt < 4; ++mt)
            #pragma unroll
            for (int nt = 0; nt < 2; ++nt) {
                const int p = h*32 + nt*16 + l15;
                const int n0 = g*64 + mt*16 + kg*4;
                unsigned int lo = pack2bf(fmaxf(acc[mt][nt][0], 0.f),
                                          fmaxf(acc[mt][nt][1], 0.f));
                unsigned int hi = pack2bf(fmaxf(acc[mt][nt][2], 0.f),
                                          fmaxf(acc[mt][nt][3], 0.f));
                *(uint2*)(Act + swz(p, n0)) = make_uint2(lo, hi);
            }
    }
    __syncthreads();                    // [2] Act W->R boundary

    ACC_CLEAR()
    // ---- layer 1: 8 K-slices, barrier-free (af streamed from L2/L1) ----
    #pragma unroll
    for (int s = 0; s < 8; ++s) {
        KSLICE_BODY(W1e + s * SLICE_ELEMS, s*32)
    }
    __syncthreads();                    // [3] all Act reads done (R->W boundary)

    // ---- layer-1 epilogue: bias+relu -> Act in place ----
    #pragma unroll
    for (int mt = 0; mt < 4; ++mt) {
        const int n0 = g*64 + mt*16 + kg*4;
        const f32x4 bb = b1v[mt];
        #pragma unroll
        for (int nt = 0; nt < 2; ++nt) {
            const int p = h*32 + nt*16 + l15;
            unsigned int lo = pack2bf(fmaxf(acc[mt][nt][0] + bb[0], 0.f),
                                      fmaxf(acc[mt][nt][1] + bb[1], 0.f));
            unsigned int hi = pack2bf(fmaxf(acc[mt][nt][2] + bb[2], 0.f),
                                      fmaxf(acc[mt][nt][3] + bb[3], 0.f));
            *(uint2*)(Act + swz(p, n0)) = make_uint2(lo, hi);
        }
    }
    __syncthreads();                    // [4] Act W->R boundary

    ACC_CLEAR()
    // ---- layer 2: 8 K-slices, barrier-free ----
    #pragma unroll
    for (int s = 0; s < 8; ++s) {
        KSLICE_BODY(W2e + s * SLICE_ELEMS, s*32)
    }

    // ---- fused layer-2 epilogue + layer 3 (fp32, in registers) ----
    {
        f32x4 bbv[4], w3v[4];
        #pragma unroll
        for (int mt = 0; mt < 4; ++mt) {
            const int nb = g*64 + mt*16 + kg*4;
            bbv[mt] = *(const f32x4*)(b2 + e*HD + nb);
            w3v[mt] = *(const f32x4*)(W3 + e*HD + nb);
        }
        #pragma unroll
        for (int nt = 0; nt < 2; ++nt) {
            float s = 0.f;
            #pragma unroll
            for (int mt = 0; mt < 4; ++mt)
                #pragma unroll
                for (int r = 0; r < 4; ++r)
                    s += fmaxf(acc[mt][nt][r] + bbv[mt][r], 0.f) * w3v[mt][r];
            s += __shfl_xor(s, 16);   // reduce over kg (4 lanes per point)
            s += __shfl_xor(s, 32);
            if (kg == 0) pscr[(h*32 + nt*16 + l15) * 4 + g] = s;
        }
    }
    __syncthreads();                    // [5] pscr W->R boundary
    if (t < NT) {
        f32x4 v = *(const f32x4*)(pscr + t * 4);
        int p = p0 + t;
        if (p < npts) ws[e * npts + p] = v[0] + v[1] + v[2] + v[3] + b3[e];
    }
}

// Max over the 8 experts' partials.
__global__ void moe_reduce(const float* __restrict__ ws, float* __restrict__ out, int npts) {
    int p = blockIdx.x * 256 + threadIdx.x;
    if (p >= npts) return;
    float m = ws[p];
    #pragma unroll
    for (int e = 1; e < NE; ++e) m = fmaxf(m, ws[e * npts + p]);
    out[p] = m;
}

extern "C" void kernel_launch(void* const* d_in, const int* in_sizes, int n_in,
                              void* d_out, int out_size, void* d_ws, size_t ws_size,
                              hipStream_t stream) {
    const float* coords = (const float*)d_in[0];
    const float* W0 = (const float*)d_in[1];
    const float* b0 = (const float*)d_in[2];
    const float* W1 = (const float*)d_in[3];
    const float* b1 = (const float*)d_in[4];
    const float* W2 = (const float*)d_in[5];
    const float* b2 = (const float*)d_in[6];
    const float* W3 = (const float*)d_in[7];
    const float* b3 = (const float*)d_in[8];
    const int npts = in_sizes[0] / 3;

    unsigned short* W1p = (unsigned short*)d_ws;                   // 1 MB
    unsigned short* W2p = W1p + NE * 8 * SLICE_ELEMS;              // 1 MB
    unsigned short* W0k = W2p + NE * 8 * SLICE_ELEMS;              // 128 KB
    float* eout = (float*)(W0k + NE * SLICE_ELEMS);                // 3.2 MB

    const int PREP_TOT = NE * 8 * SLICE_ELEMS;
    prep_weights<<<(PREP_TOT + 255) / 256, 256, 0, stream>>>(W1, W2, W1p, W2p);
    prep_w0<<<(NE * HD + 255) / 256, 256, 0, stream>>>(W0, b0, W0k);

    int ntiles = (npts + NT - 1) / NT;
    moe_expert<<<ntiles * NE, NTHREADS, 0, stream>>>(
        coords, npts, W0k, b1, W1p, W2p, b2, W3, b3, eout);

    moe_reduce<<<(npts + 255) / 256, 256, 0, stream>>>(eout, (float*)d_out, npts);
}

// Round 29
// 233.334 us; speedup vs baseline: 1.8205x; 1.8205x over previous
//
#include <hip/hip_runtime.h>
#include <hip/hip_bf16.h>

#define NE 8
#define HD 256
#define NT 64
#define NTHREADS 256
#define WPITCH 32
#define SLICE_ELEMS (HD * WPITCH)      // 8192 elems = 16384 B per K-slice

typedef __attribute__((ext_vector_type(8))) short short8;
typedef __attribute__((ext_vector_type(4))) float f32x4;

__device__ __forceinline__ unsigned short f2bf_u16(float f) {
    union { __hip_bfloat16 b; unsigned short u; } v;
    v.b = __float2bfloat16(f);          // HW RNE convert
    return v.u;
}
__device__ __forceinline__ unsigned int pack2bf(float lo, float hi) {
    return (unsigned int)f2bf_u16(lo) | ((unsigned int)f2bf_u16(hi) << 16);
}
// hi/lo bf16 split: v ≈ hi + lo with |v - hi - lo| <= 2^-16 |v|.
__device__ __forceinline__ void bfsplit(float v, unsigned short& hi, unsigned short& lo) {
    hi = f2bf_u16(v);
    union { unsigned int u; float f; } c; c.u = ((unsigned int)hi) << 16;
    lo = f2bf_u16(v - c.f);
}
// Act LDS swizzle (element units), proven in R12/R17.
__device__ __forceinline__ int swz(int row, int col) {
    return row * HD + (col ^ ((row & 7) << 3));
}

// Weights pre-swizzled: Wp[e][slice s][n][32], [n][kk] = W[k=s*32+kk][n].
__global__ void prep_weights(const float* __restrict__ W1, const float* __restrict__ W2,
                             unsigned short* __restrict__ W1p, unsigned short* __restrict__ W2p) {
    int idx = blockIdx.x * blockDim.x + threadIdx.x;
    const int TOT = NE * 8 * SLICE_ELEMS;
    if (idx >= TOT) return;
    int kk = idx & 31;
    int n  = (idx >> 5) & 255;
    int s  = (idx >> 13) & 7;
    int e  = idx >> 16;
    int k = s * 32 + kk;
    W1p[idx] = f2bf_u16(W1[(e * HD + k) * HD + n]);
    W2p[idx] = f2bf_u16(W2[(e * HD + k) * HD + n]);
}

// Layer-0 as a K=32 MFMA slice (bias folded in; pairs with cbufK B-slots).
__global__ void prep_w0(const float* __restrict__ W0, const float* __restrict__ b0,
                        unsigned short* __restrict__ W0k) {
    int idx = blockIdx.x * blockDim.x + threadIdx.x;   // e*HD + n
    if (idx >= NE * HD) return;
    int n = idx & 255, e = idx >> 8;
    float wx = W0[(e*3+0)*HD + n], wy = W0[(e*3+1)*HD + n], wz = W0[(e*3+2)*HD + n];
    float bb = b0[e*HD + n];
    unsigned short xh,xl,yh,yl,zh,zl,bh,bl;
    bfsplit(wx,xh,xl); bfsplit(wy,yh,yl); bfsplit(wz,zh,zl); bfsplit(bb,bh,bl);
    unsigned short s[32] = {xh,xh,xl, yh,yh,yl, zh,zh,zl, bh,bl};  // rest zero
    unsigned short* dst = W0k + idx * 32;
    #pragma unroll
    for (int i = 0; i < 32; ++i) dst[i] = s[i];
}

// One K-slice: 4 af DIRECT FROM L2 (own neuron quarter, wave-private — no LDS,
// no barriers) x 4 bf (Act LDS, all 64 points) -> 16 MFMA.
#define KSLICE_MFMA(AF0, AF1, AF2, AF3, K0)                                                  \
    {                                                                                        \
        const int k0 = (K0) + kg*8;                                                          \
        _Pragma("unroll")                                                                    \
        for (int nt = 0; nt < 4; ++nt) {                                                     \
            short8 bf = *(const short8*)(Act + swz(nt*16 + l15, k0));                        \
            acc[0][nt] = __builtin_amdgcn_mfma_f32_16x16x32_bf16(AF0, bf, acc[0][nt], 0,0,0);\
            acc[1][nt] = __builtin_amdgcn_mfma_f32_16x16x32_bf16(AF1, bf, acc[1][nt], 0,0,0);\
            acc[2][nt] = __builtin_amdgcn_mfma_f32_16x16x32_bf16(AF2, bf, acc[2][nt], 0,0,0);\
            acc[3][nt] = __builtin_amdgcn_mfma_f32_16x16x32_bf16(AF3, bf, acc[3][nt], 0,0,0);\
        }                                                                                    \
    }

#define KSLICE_BODY(WSRC, K0)                                                                \
    {                                                                                        \
        const unsigned short* Ar = (WSRC) + (g*64 + l15) * WPITCH + kg*8;                    \
        short8 af0 = *(const short8*)(Ar + 0*16*WPITCH);                                     \
        short8 af1 = *(const short8*)(Ar + 1*16*WPITCH);                                     \
        short8 af2 = *(const short8*)(Ar + 2*16*WPITCH);                                     \
        short8 af3 = *(const short8*)(Ar + 3*16*WPITCH);                                     \
        KSLICE_MFMA(af0, af1, af2, af3, K0)                                                  \
    }

// acc init = bias (MFMA C-in accumulates) — deletes the epilogue adds.
#define ACC_INIT_BIAS(BV)                                     \
    _Pragma("unroll")                                         \
    for (int mt = 0; mt < 4; ++mt)                            \
        _Pragma("unroll")                                     \
        for (int nt = 0; nt < 4; ++nt)                        \
            acc[mt][nt] = (BV)[mt];

// One expert per block: blockIdx = tile*8 + e (XCD round-robin -> blocks on an
// XCD share the expert; weights L2-resident). 4 waves, wave g owns neurons
// [g*64,+64) x ALL 64 points (square tile). 36 KB LDS; 5 barriers; K-loops
// barrier-free. (256,3): no spill (R23's (,4) pinned 64 VGPR and spilled).
__global__ __launch_bounds__(NTHREADS, 3) void moe_expert(
    const float* __restrict__ coords, int npts,
    const unsigned short* __restrict__ W0k, const float* __restrict__ b1,
    const unsigned short* __restrict__ W1p,
    const unsigned short* __restrict__ W2p, const float* __restrict__ b2,
    const float* __restrict__ W3, const float* __restrict__ b3,
    float* __restrict__ ws)
{
    __shared__ __align__(16) unsigned short Act[NT * HD];      // 32 KB
    __shared__ __align__(16) unsigned char aux[NT * 32 * 2];   // 4 KB: cbufK / pscr
    unsigned short* cbufK = (unsigned short*)aux;   // phases 0-1 only
    float* pscr = (float*)aux;                      // tail only (disjoint in time)

    const int t = threadIdx.x;
    const int lane = t & 63;
    const int g = t >> 6;       // 0..3: neuron group of 64
    const int l15 = lane & 15;
    const int kg = lane >> 4;
    const int e = blockIdx.x & 7;
    const int p0 = (blockIdx.x >> 3) * NT;

    const unsigned short* W0e = W0k + e * SLICE_ELEMS;
    const unsigned short* W1e = W1p + e * 8 * SLICE_ELEMS;
    const unsigned short* W2e = W2p + e * 8 * SLICE_ELEMS;

    // ---- pre-barrier loads: W0 af frags (hide L2 latency under barrier [1]) ----
    const unsigned short* Ar0 = W0e + (g*64 + l15) * WPITCH + kg*8;
    short8 paf0 = *(const short8*)(Ar0 + 0*16*WPITCH);
    short8 paf1 = *(const short8*)(Ar0 + 1*16*WPITCH);
    short8 paf2 = *(const short8*)(Ar0 + 2*16*WPITCH);
    short8 paf3 = *(const short8*)(Ar0 + 3*16*WPITCH);

    // ---- phase 0: build per-point L0 B-slots (hi/lo split) ----
    if (t < NT) {
        int p = p0 + t;
        int pc = p < npts ? p : npts - 1;      // clamp; store masked later
        float x = coords[pc*3], y = coords[pc*3+1], z = coords[pc*3+2];
        unsigned short xh,xl,yh,yl,zh,zl;
        bfsplit(x,xh,xl); bfsplit(y,yh,yl); bfsplit(z,zh,zl);
        const unsigned short ONE = 0x3F80;     // bf16(1.0)
        union { unsigned short s[32]; uint4 q[4]; } pk;
        #pragma unroll
        for (int i = 0; i < 32; ++i) pk.s[i] = 0;
        pk.s[0]=xh; pk.s[1]=xl; pk.s[2]=xh;
        pk.s[3]=yh; pk.s[4]=yl; pk.s[5]=yh;
        pk.s[6]=zh; pk.s[7]=zl; pk.s[8]=zh;
        pk.s[9]=ONE; pk.s[10]=ONE;
        uint4* dst = (uint4*)(cbufK + t * 32);
        dst[0]=pk.q[0]; dst[1]=pk.q[1]; dst[2]=pk.q[2]; dst[3]=pk.q[3];
    }
    f32x4 b1v[4];
    #pragma unroll
    for (int mt = 0; mt < 4; ++mt)
        b1v[mt] = *(const f32x4*)(b1 + e*HD + g*64 + mt*16 + kg*4);
    __syncthreads();                    // [1] cbufK visible

    f32x4 acc[4][4];
    #pragma unroll
    for (int mt = 0; mt < 4; ++mt)
        #pragma unroll
        for (int nt = 0; nt < 4; ++nt)
            acc[mt][nt] = (f32x4){0.f, 0.f, 0.f, 0.f};

    // ---- phase 1: L0 as one MFMA K-slice (prefetched af, bias in slots) ----
    {
        #pragma unroll
        for (int nt = 0; nt < 4; ++nt) {
            short8 bf = *(const short8*)(cbufK + (nt*16 + l15) * 32 + kg*8);
            acc[0][nt] = __builtin_amdgcn_mfma_f32_16x16x32_bf16(paf0, bf, acc[0][nt], 0,0,0);
            acc[1][nt] = __builtin_amdgcn_mfma_f32_16x16x32_bf16(paf1, bf, acc[1][nt], 0,0,0);
            acc[2][nt] = __builtin_amdgcn_mfma_f32_16x16x32_bf16(paf2, bf, acc[2][nt], 0,0,0);
            acc[3][nt] = __builtin_amdgcn_mfma_f32_16x16x32_bf16(paf3, bf, acc[3][nt], 0,0,0);
        }
        // prefetch layer-1 slice 0 af (hides under epilogue + barrier [2])
        const unsigned short* Ar1 = W1e + (g*64 + l15) * WPITCH + kg*8;
        paf0 = *(const short8*)(Ar1 + 0*16*WPITCH);
        paf1 = *(const short8*)(Ar1 + 1*16*WPITCH);
        paf2 = *(const short8*)(Ar1 + 2*16*WPITCH);
        paf3 = *(const short8*)(Ar1 + 3*16*WPITCH);
        // L0 epilogue: relu + pack -> Act (bias already in the MFMA slots)
        #pragma unroll
        for (int mt = 0; mt < 4; ++mt)
            #pragma unroll
            for (int nt = 0; nt < 4; ++nt) {
                const int p = nt*16 + l15;
                const int n0 = g*64 + mt*16 + kg*4;
                unsigned int lo = pack2bf(fmaxf(acc[mt][nt][0], 0.f),
                                          fmaxf(acc[mt][nt][1], 0.f));
                unsigned int hi = pack2bf(fmaxf(acc[mt][nt][2], 0.f),
                                          fmaxf(acc[mt][nt][3], 0.f));
                *(uint2*)(Act + swz(p, n0)) = make_uint2(lo, hi);
            }
    }
    __syncthreads();                    // [2] Act W->R boundary

    ACC_INIT_BIAS(b1v)                  // bias pre-loaded into C
    // ---- layer 1: slice 0 from prefetched af, then 7 slices barrier-free ----
    KSLICE_MFMA(paf0, paf1, paf2, paf3, 0)
    #pragma unroll
    for (int s = 1; s < 8; ++s) {
        KSLICE_BODY(W1e + s * SLICE_ELEMS, s*32)
    }
    // prefetch layer-2 slice 0 af (hides under epilogue + barriers [3][4])
    {
        const unsigned short* Ar2 = W2e + (g*64 + l15) * WPITCH + kg*8;
        paf0 = *(const short8*)(Ar2 + 0*16*WPITCH);
        paf1 = *(const short8*)(Ar2 + 1*16*WPITCH);
        paf2 = *(const short8*)(Ar2 + 2*16*WPITCH);
        paf3 = *(const short8*)(Ar2 + 3*16*WPITCH);
    }
    __syncthreads();                    // [3] all Act reads done (R->W boundary)

    // ---- layer-1 epilogue: relu (bias already in acc) -> Act in place ----
    #pragma unroll
    for (int mt = 0; mt < 4; ++mt) {
        const int n0 = g*64 + mt*16 + kg*4;
        #pragma unroll
        for (int nt = 0; nt < 4; ++nt) {
            const int p = nt*16 + l15;
            unsigned int lo = pack2bf(fmaxf(acc[mt][nt][0], 0.f),
                                      fmaxf(acc[mt][nt][1], 0.f));
            unsigned int hi = pack2bf(fmaxf(acc[mt][nt][2], 0.f),
                                      fmaxf(acc[mt][nt][3], 0.f));
            *(uint2*)(Act + swz(p, n0)) = make_uint2(lo, hi);
        }
    }
    f32x4 b2v[4], w3v[4];
    #pragma unroll
    for (int mt = 0; mt < 4; ++mt) {
        const int nb = g*64 + mt*16 + kg*4;
        b2v[mt] = *(const f32x4*)(b2 + e*HD + nb);
        w3v[mt] = *(const f32x4*)(W3 + e*HD + nb);
    }
    __syncthreads();                    // [4] Act W->R boundary

    ACC_INIT_BIAS(b2v)                  // bias pre-loaded into C
    // ---- layer 2: slice 0 from prefetched af, then 7 slices barrier-free ----
    KSLICE_MFMA(paf0, paf1, paf2, paf3, 0)
    #pragma unroll
    for (int s = 1; s < 8; ++s) {
        KSLICE_BODY(W2e + s * SLICE_ELEMS, s*32)
    }

    // ---- fused layer-2 epilogue + layer 3 (fp32, in registers) ----
    #pragma unroll
    for (int nt = 0; nt < 4; ++nt) {
        float s = 0.f;
        #pragma unroll
        for (int mt = 0; mt < 4; ++mt)
            #pragma unroll
            for (int r = 0; r < 4; ++r)
                s += fmaxf(acc[mt][nt][r], 0.f) * w3v[mt][r];
        s += __shfl_xor(s, 16);   // reduce over kg (4 lanes per point)
        s += __shfl_xor(s, 32);
        if (kg == 0) pscr[(nt*16 + l15) * 4 + g] = s;   // pscr aliases cbufK
    }                                                   // (last read: phase 1)
    __syncthreads();                    // [5] pscr W->R boundary
    if (t < NT) {
        f32x4 v = *(const f32x4*)(pscr + t * 4);
        int p = p0 + t;
        if (p < npts) ws[e * npts + p] = v[0] + v[1] + v[2] + v[3] + b3[e];
    }
}

// Max over the 8 experts' partials.
__global__ void moe_reduce(const float* __restrict__ ws, float* __restrict__ out, int npts) {
    int p = blockIdx.x * 256 + threadIdx.x;
    if (p >= npts) return;
    float m = ws[p];
    #pragma unroll
    for (int e = 1; e < NE; ++e) m = fmaxf(m, ws[e * npts + p]);
    out[p] = m;
}

extern "C" void kernel_launch(void* const* d_in, const int* in_sizes, int n_in,
                              void* d_out, int out_size, void* d_ws, size_t ws_size,
                              hipStream_t stream) {
    const float* coords = (const float*)d_in[0];
    const float* W0 = (const float*)d_in[1];
    const float* b0 = (const float*)d_in[2];
    const float* W1 = (const float*)d_in[3];
    const float* b1 = (const float*)d_in[4];
    const float* W2 = (const float*)d_in[5];
    const float* b2 = (const float*)d_in[6];
    const float* W3 = (const float*)d_in[7];
    const float* b3 = (const float*)d_in[8];
    const int npts = in_sizes[0] / 3;

    unsigned short* W1p = (unsigned short*)d_ws;                   // 1 MB
    unsigned short* W2p = W1p + NE * 8 * SLICE_ELEMS;              // 1 MB
    unsigned short* W0k = W2p + NE * 8 * SLICE_ELEMS;              // 128 KB
    float* eout = (float*)(W0k + NE * SLICE_ELEMS);                // 3.2 MB

    const int PREP_TOT = NE * 8 * SLICE_ELEMS;
    prep_weights<<<(PREP_TOT + 255) / 256, 256, 0, stream>>>(W1, W2, W1p, W2p);
    prep_w0<<<(NE * HD + 255) / 256, 256, 0, stream>>>(W0, b0, W0k);

    int ntiles = (npts + NT - 1) / NT;
    moe_expert<<<ntiles * NE, NTHREADS, 0, stream>>>(
        coords, npts, W0k, b1, W1p, W2p, b2, W3, b3, eout);

    moe_reduce<<<(npts + 255) / 256, 256, 0, stream>>>(eout, (float*)d_out, npts);
}

// Round 30
// 232.257 us; speedup vs baseline: 1.8289x; 1.0046x over previous
//
#include <hip/hip_runtime.h>
#include <hip/hip_bf16.h>

#define NE 8
#define HD 256
#define NT 64
#define NTHREADS 256
#define WPITCH 32
#define SLICE_ELEMS (HD * WPITCH)      // 8192 elems = 16384 B per K-slice

typedef __attribute__((ext_vector_type(8))) short short8;
typedef __attribute__((ext_vector_type(4))) float f32x4;

__device__ __forceinline__ unsigned short f2bf_u16(float f) {
    union { __hip_bfloat16 b; unsigned short u; } v;
    v.b = __float2bfloat16(f);          // HW RNE convert
    return v.u;
}
__device__ __forceinline__ unsigned int pack2bf(float lo, float hi) {
    return (unsigned int)f2bf_u16(lo) | ((unsigned int)f2bf_u16(hi) << 16);
}
// hi/lo bf16 split: v ≈ hi + lo with |v - hi - lo| <= 2^-16 |v|.
__device__ __forceinline__ void bfsplit(float v, unsigned short& hi, unsigned short& lo) {
    hi = f2bf_u16(v);
    union { unsigned int u; float f; } c; c.u = ((unsigned int)hi) << 16;
    lo = f2bf_u16(v - c.f);
}
// Act LDS swizzle (element units), proven in R12/R17.
__device__ __forceinline__ int swz(int row, int col) {
    return row * HD + (col ^ ((row & 7) << 3));
}

// Weights pre-swizzled: Wp[e][slice s][n][32], [n][kk] = W[k=s*32+kk][n].
__global__ void prep_weights(const float* __restrict__ W1, const float* __restrict__ W2,
                             unsigned short* __restrict__ W1p, unsigned short* __restrict__ W2p) {
    int idx = blockIdx.x * blockDim.x + threadIdx.x;
    const int TOT = NE * 8 * SLICE_ELEMS;
    if (idx >= TOT) return;
    int kk = idx & 31;
    int n  = (idx >> 5) & 255;
    int s  = (idx >> 13) & 7;
    int e  = idx >> 16;
    int k = s * 32 + kk;
    W1p[idx] = f2bf_u16(W1[(e * HD + k) * HD + n]);
    W2p[idx] = f2bf_u16(W2[(e * HD + k) * HD + n]);
}

// Layer-0 as a K=32 MFMA slice (bias folded in; pairs with cbufK B-slots).
__global__ void prep_w0(const float* __restrict__ W0, const float* __restrict__ b0,
                        unsigned short* __restrict__ W0k) {
    int idx = blockIdx.x * blockDim.x + threadIdx.x;   // e*HD + n
    if (idx >= NE * HD) return;
    int n = idx & 255, e = idx >> 8;
    float wx = W0[(e*3+0)*HD + n], wy = W0[(e*3+1)*HD + n], wz = W0[(e*3+2)*HD + n];
    float bb = b0[e*HD + n];
    unsigned short xh,xl,yh,yl,zh,zl,bh,bl;
    bfsplit(wx,xh,xl); bfsplit(wy,yh,yl); bfsplit(wz,zh,zl); bfsplit(bb,bh,bl);
    unsigned short s[32] = {xh,xh,xl, yh,yh,yl, zh,zh,zl, bh,bl};  // rest zero
    unsigned short* dst = W0k + idx * 32;
    #pragma unroll
    for (int i = 0; i < 32; ++i) dst[i] = s[i];
}

// One K-slice: 4 af DIRECT FROM L2 (own neuron quarter, wave-private — no LDS,
// no barriers) x 4 bf (Act LDS, all 64 points) -> 16 MFMA.
#define KSLICE_MFMA(AF0, AF1, AF2, AF3, K0)                                                  \
    {                                                                                        \
        const int k0 = (K0) + kg*8;                                                          \
        _Pragma("unroll")                                                                    \
        for (int nt = 0; nt < 4; ++nt) {                                                     \
            short8 bf = *(const short8*)(Act + swz(nt*16 + l15, k0));                        \
            acc[0][nt] = __builtin_amdgcn_mfma_f32_16x16x32_bf16(AF0, bf, acc[0][nt], 0,0,0);\
            acc[1][nt] = __builtin_amdgcn_mfma_f32_16x16x32_bf16(AF1, bf, acc[1][nt], 0,0,0);\
            acc[2][nt] = __builtin_amdgcn_mfma_f32_16x16x32_bf16(AF2, bf, acc[2][nt], 0,0,0);\
            acc[3][nt] = __builtin_amdgcn_mfma_f32_16x16x32_bf16(AF3, bf, acc[3][nt], 0,0,0);\
        }                                                                                    \
    }

#define KSLICE_BODY(WSRC, K0)                                                                \
    {                                                                                        \
        const unsigned short* Ar = (WSRC) + (g*64 + l15) * WPITCH + kg*8;                    \
        short8 af0 = *(const short8*)(Ar + 0*16*WPITCH);                                     \
        short8 af1 = *(const short8*)(Ar + 1*16*WPITCH);                                     \
        short8 af2 = *(const short8*)(Ar + 2*16*WPITCH);                                     \
        short8 af3 = *(const short8*)(Ar + 3*16*WPITCH);                                     \
        KSLICE_MFMA(af0, af1, af2, af3, K0)                                                  \
    }

// acc init = bias (MFMA C-in accumulates) — deletes the epilogue adds.
#define ACC_INIT_BIAS(BV)                                     \
    _Pragma("unroll")                                         \
    for (int mt = 0; mt < 4; ++mt)                            \
        _Pragma("unroll")                                     \
        for (int nt = 0; nt < 4; ++nt)                        \
            acc[mt][nt] = (BV)[mt];

// One expert per block: blockIdx = tile*8 + e (XCD round-robin -> blocks on an
// XCD share the expert; weights L2-resident). 4 waves, wave g owns neurons
// [g*64,+64) x ALL 64 points. LDS = Act ONLY (cbufK and pscr alias into it;
// R27-proven pattern) = 32768 B exactly -> target 4 blocks/CU. K-loops
// barrier-free; 7 barriers/block. (256,3): no spill.
__global__ __launch_bounds__(NTHREADS, 3) void moe_expert(
    const float* __restrict__ coords, int npts,
    const unsigned short* __restrict__ W0k, const float* __restrict__ b1,
    const unsigned short* __restrict__ W1p,
    const unsigned short* __restrict__ W2p, const float* __restrict__ b2,
    const float* __restrict__ W3, const float* __restrict__ b3,
    float* __restrict__ ws)
{
    __shared__ __align__(16) unsigned short Act[NT * HD];      // 32 KB (ONLY buffer)
    unsigned short* cbufK = Act;        // alias: live phase 0-1 only
    float* pscr = (float*)Act;          // alias: live tail only

    const int t = threadIdx.x;
    const int lane = t & 63;
    const int g = t >> 6;       // 0..3: neuron group of 64
    const int l15 = lane & 15;
    const int kg = lane >> 4;
    const int e = blockIdx.x & 7;
    const int p0 = (blockIdx.x >> 3) * NT;

    const unsigned short* W0e = W0k + e * SLICE_ELEMS;
    const unsigned short* W1e = W1p + e * 8 * SLICE_ELEMS;
    const unsigned short* W2e = W2p + e * 8 * SLICE_ELEMS;

    // ---- pre-barrier loads: W0 af frags (hide L2 latency under barrier [1]) ----
    const unsigned short* Ar0 = W0e + (g*64 + l15) * WPITCH + kg*8;
    short8 paf0 = *(const short8*)(Ar0 + 0*16*WPITCH);
    short8 paf1 = *(const short8*)(Ar0 + 1*16*WPITCH);
    short8 paf2 = *(const short8*)(Ar0 + 2*16*WPITCH);
    short8 paf3 = *(const short8*)(Ar0 + 3*16*WPITCH);

    // ---- phase 0: build per-point L0 B-slots (hi/lo split) into cbufK ----
    if (t < NT) {
        int p = p0 + t;
        int pc = p < npts ? p : npts - 1;      // clamp; store masked later
        float x = coords[pc*3], y = coords[pc*3+1], z = coords[pc*3+2];
        unsigned short xh,xl,yh,yl,zh,zl;
        bfsplit(x,xh,xl); bfsplit(y,yh,yl); bfsplit(z,zh,zl);
        const unsigned short ONE = 0x3F80;     // bf16(1.0)
        union { unsigned short s[32]; uint4 q[4]; } pk;
        #pragma unroll
        for (int i = 0; i < 32; ++i) pk.s[i] = 0;
        pk.s[0]=xh; pk.s[1]=xl; pk.s[2]=xh;
        pk.s[3]=yh; pk.s[4]=yl; pk.s[5]=yh;
        pk.s[6]=zh; pk.s[7]=zl; pk.s[8]=zh;
        pk.s[9]=ONE; pk.s[10]=ONE;
        uint4* dst = (uint4*)(cbufK + t * 32);
        dst[0]=pk.q[0]; dst[1]=pk.q[1]; dst[2]=pk.q[2]; dst[3]=pk.q[3];
    }
    f32x4 b1v[4];
    #pragma unroll
    for (int mt = 0; mt < 4; ++mt)
        b1v[mt] = *(const f32x4*)(b1 + e*HD + g*64 + mt*16 + kg*4);
    __syncthreads();                    // [1] cbufK visible

    f32x4 acc[4][4];
    #pragma unroll
    for (int mt = 0; mt < 4; ++mt)
        #pragma unroll
        for (int nt = 0; nt < 4; ++nt)
            acc[mt][nt] = (f32x4){0.f, 0.f, 0.f, 0.f};

    // ---- phase 1: L0 as one MFMA K-slice (prefetched af, bias in slots) ----
    {
        #pragma unroll
        for (int nt = 0; nt < 4; ++nt) {
            short8 bf = *(const short8*)(cbufK + (nt*16 + l15) * 32 + kg*8);
            acc[0][nt] = __builtin_amdgcn_mfma_f32_16x16x32_bf16(paf0, bf, acc[0][nt], 0,0,0);
            acc[1][nt] = __builtin_amdgcn_mfma_f32_16x16x32_bf16(paf1, bf, acc[1][nt], 0,0,0);
            acc[2][nt] = __builtin_amdgcn_mfma_f32_16x16x32_bf16(paf2, bf, acc[2][nt], 0,0,0);
            acc[3][nt] = __builtin_amdgcn_mfma_f32_16x16x32_bf16(paf3, bf, acc[3][nt], 0,0,0);
        }
        // prefetch layer-1 slice 0 af (hides under barrier [1b] + epilogue)
        const unsigned short* Ar1 = W1e + (g*64 + l15) * WPITCH + kg*8;
        paf0 = *(const short8*)(Ar1 + 0*16*WPITCH);
        paf1 = *(const short8*)(Ar1 + 1*16*WPITCH);
        paf2 = *(const short8*)(Ar1 + 2*16*WPITCH);
        paf3 = *(const short8*)(Ar1 + 3*16*WPITCH);
    }
    __syncthreads();                    // [1b] all cbufK reads done (alias clobber)
    // ---- L0 epilogue: relu + pack -> Act (bias already in the MFMA slots) ----
    #pragma unroll
    for (int mt = 0; mt < 4; ++mt)
        #pragma unroll
        for (int nt = 0; nt < 4; ++nt) {
            const int p = nt*16 + l15;
            const int n0 = g*64 + mt*16 + kg*4;
            unsigned int lo = pack2bf(fmaxf(acc[mt][nt][0], 0.f),
                                      fmaxf(acc[mt][nt][1], 0.f));
            unsigned int hi = pack2bf(fmaxf(acc[mt][nt][2], 0.f),
                                      fmaxf(acc[mt][nt][3], 0.f));
            *(uint2*)(Act + swz(p, n0)) = make_uint2(lo, hi);
        }
    __syncthreads();                    // [2] Act W->R boundary

    ACC_INIT_BIAS(b1v)                  // bias pre-loaded into C
    // ---- layer 1: slice 0 from prefetched af, then 7 slices barrier-free ----
    KSLICE_MFMA(paf0, paf1, paf2, paf3, 0)
    #pragma unroll
    for (int s = 1; s < 8; ++s) {
        KSLICE_BODY(W1e + s * SLICE_ELEMS, s*32)
    }
    // prefetch layer-2 slice 0 af (hides under epilogue + barriers [3][4])
    {
        const unsigned short* Ar2 = W2e + (g*64 + l15) * WPITCH + kg*8;
        paf0 = *(const short8*)(Ar2 + 0*16*WPITCH);
        paf1 = *(const short8*)(Ar2 + 1*16*WPITCH);
        paf2 = *(const short8*)(Ar2 + 2*16*WPITCH);
        paf3 = *(const short8*)(Ar2 + 3*16*WPITCH);
    }
    __syncthreads();                    // [3] all Act reads done (R->W boundary)

    // ---- layer-1 epilogue: relu (bias already in acc) -> Act in place ----
    #pragma unroll
    for (int mt = 0; mt < 4; ++mt) {
        const int n0 = g*64 + mt*16 + kg*4;
        #pragma unroll
        for (int nt = 0; nt < 4; ++nt) {
            const int p = nt*16 + l15;
            unsigned int lo = pack2bf(fmaxf(acc[mt][nt][0], 0.f),
                                      fmaxf(acc[mt][nt][1], 0.f));
            unsigned int hi = pack2bf(fmaxf(acc[mt][nt][2], 0.f),
                                      fmaxf(acc[mt][nt][3], 0.f));
            *(uint2*)(Act + swz(p, n0)) = make_uint2(lo, hi);
        }
    }
    f32x4 b2v[4], w3v[4];
    #pragma unroll
    for (int mt = 0; mt < 4; ++mt) {
        const int nb = g*64 + mt*16 + kg*4;
        b2v[mt] = *(const f32x4*)(b2 + e*HD + nb);
        w3v[mt] = *(const f32x4*)(W3 + e*HD + nb);
    }
    __syncthreads();                    // [4] Act W->R boundary

    ACC_INIT_BIAS(b2v)                  // bias pre-loaded into C
    // ---- layer 2: slice 0 from prefetched af, then 7 slices barrier-free ----
    KSLICE_MFMA(paf0, paf1, paf2, paf3, 0)
    #pragma unroll
    for (int s = 1; s < 8; ++s) {
        KSLICE_BODY(W2e + s * SLICE_ELEMS, s*32)
    }
    __syncthreads();                    // [4b] all Act reads done (pscr alias safe)

    // ---- fused layer-2 epilogue + layer 3 (fp32, in registers) ----
    #pragma unroll
    for (int nt = 0; nt < 4; ++nt) {
        float s = 0.f;
        #pragma unroll
        for (int mt = 0; mt < 4; ++mt)
            #pragma unroll
            for (int r = 0; r < 4; ++r)
                s += fmaxf(acc[mt][nt][r], 0.f) * w3v[mt][r];
        s += __shfl_xor(s, 16);   // reduce over kg (4 lanes per point)
        s += __shfl_xor(s, 32);
        if (kg == 0) pscr[(nt*16 + l15) * 4 + g] = s;   // pscr aliases Act
    }
    __syncthreads();                    // [5] pscr W->R boundary
    if (t < NT) {
        f32x4 v = *(const f32x4*)(pscr + t * 4);
        int p = p0 + t;
        if (p < npts) ws[e * npts + p] = v[0] + v[1] + v[2] + v[3] + b3[e];
    }
}

// Max over the 8 experts' partials.
__global__ void moe_reduce(const float* __restrict__ ws, float* __restrict__ out, int npts) {
    int p = blockIdx.x * 256 + threadIdx.x;
    if (p >= npts) return;
    float m = ws[p];
    #pragma unroll
    for (int e = 1; e < NE; ++e) m = fmaxf(m, ws[e * npts + p]);
    out[p] = m;
}

extern "C" void kernel_launch(void* const* d_in, const int* in_sizes, int n_in,
                              void* d_out, int out_size, void* d_ws, size_t ws_size,
                              hipStream_t stream) {
    const float* coords = (const float*)d_in[0];
    const float* W0 = (const float*)d_in[1];
    const float* b0 = (const float*)d_in[2];
    const float* W1 = (const float*)d_in[3];
    const float* b1 = (const float*)d_in[4];
    const float* W2 = (const float*)d_in[5];
    const float* b2 = (const float*)d_in[6];
    const float* W3 = (const float*)d_in[7];
    const float* b3 = (const float*)d_in[8];
    const int npts = in_sizes[0] / 3;

    unsigned short* W1p = (unsigned short*)d_ws;                   // 1 MB
    unsigned short* W2p = W1p + NE * 8 * SLICE_ELEMS;              // 1 MB
    unsigned short* W0k = W2p + NE * 8 * SLICE_ELEMS;              // 128 KB
    float* eout = (float*)(W0k + NE * SLICE_ELEMS);                // 3.2 MB

    const int PREP_TOT = NE * 8 * SLICE_ELEMS;
    prep_weights<<<(PREP_TOT + 255) / 256, 256, 0, stream>>>(W1, W2, W1p, W2p);
    prep_w0<<<(NE * HD + 255) / 256, 256, 0, stream>>>(W0, b0, W0k);

    int ntiles = (npts + NT - 1) / NT;
    moe_expert<<<ntiles * NE, NTHREADS, 0, stream>>>(
        coords, npts, W0k, b1, W1p, W2p, b2, W3, b3, eout);

    moe_reduce<<<(npts + 255) / 256, 256, 0, stream>>>(eout, (float*)d_out, npts);
}

// Round 31
// 231.791 us; speedup vs baseline: 1.8326x; 1.0020x over previous
//
#include <hip/hip_runtime.h>
#include <hip/hip_bf16.h>

#define NE 8
#define HD 256
#define NT 64
#define NTHREADS 256
#define WPITCH 32
#define SLICE_ELEMS (HD * WPITCH)      // 8192 elems = 16384 B per K-slice

typedef __attribute__((ext_vector_type(8))) short short8;
typedef __attribute__((ext_vector_type(4))) float f32x4;

__device__ __forceinline__ unsigned short f2bf_u16(float f) {
    union { __hip_bfloat16 b; unsigned short u; } v;
    v.b = __float2bfloat16(f);          // HW RNE convert
    return v.u;
}
__device__ __forceinline__ unsigned int pack2bf(float lo, float hi) {
    return (unsigned int)f2bf_u16(lo) | ((unsigned int)f2bf_u16(hi) << 16);
}
// hi/lo bf16 split: v ≈ hi + lo with |v - hi - lo| <= 2^-16 |v|.
__device__ __forceinline__ void bfsplit(float v, unsigned short& hi, unsigned short& lo) {
    hi = f2bf_u16(v);
    union { unsigned int u; float f; } c; c.u = ((unsigned int)hi) << 16;
    lo = f2bf_u16(v - c.f);
}
// Act LDS swizzle (element units), proven in R12/R17.
__device__ __forceinline__ int swz(int row, int col) {
    return row * HD + (col ^ ((row & 7) << 3));
}

// Weights pre-swizzled: Wp[e][slice s][n][32], [n][kk] = W[k=s*32+kk][n].
__global__ void prep_weights(const float* __restrict__ W1, const float* __restrict__ W2,
                             unsigned short* __restrict__ W1p, unsigned short* __restrict__ W2p) {
    int idx = blockIdx.x * blockDim.x + threadIdx.x;
    const int TOT = NE * 8 * SLICE_ELEMS;
    if (idx >= TOT) return;
    int kk = idx & 31;
    int n  = (idx >> 5) & 255;
    int s  = (idx >> 13) & 7;
    int e  = idx >> 16;
    int k = s * 32 + kk;
    W1p[idx] = f2bf_u16(W1[(e * HD + k) * HD + n]);
    W2p[idx] = f2bf_u16(W2[(e * HD + k) * HD + n]);
}

// Layer-0 as a K=32 MFMA slice (bias folded in; pairs with cbufK B-slots).
__global__ void prep_w0(const float* __restrict__ W0, const float* __restrict__ b0,
                        unsigned short* __restrict__ W0k) {
    int idx = blockIdx.x * blockDim.x + threadIdx.x;   // e*HD + n
    if (idx >= NE * HD) return;
    int n = idx & 255, e = idx >> 8;
    float wx = W0[(e*3+0)*HD + n], wy = W0[(e*3+1)*HD + n], wz = W0[(e*3+2)*HD + n];
    float bb = b0[e*HD + n];
    unsigned short xh,xl,yh,yl,zh,zl,bh,bl;
    bfsplit(wx,xh,xl); bfsplit(wy,yh,yl); bfsplit(wz,zh,zl); bfsplit(bb,bh,bl);
    unsigned short s[32] = {xh,xh,xl, yh,yh,yl, zh,zh,zl, bh,bl};  // rest zero
    unsigned short* dst = W0k + idx * 32;
    #pragma unroll
    for (int i = 0; i < 32; ++i) dst[i] = s[i];
}

// One K-slice: 4 af DIRECT FROM L2 (own neuron quarter, wave-private — no LDS,
// no barriers) x 4 bf (Act LDS, all 64 points) -> 16 MFMA.
#define KSLICE_MFMA(AF0, AF1, AF2, AF3, K0)                                                  \
    {                                                                                        \
        const int k0 = (K0) + kg*8;                                                          \
        _Pragma("unroll")                                                                    \
        for (int nt = 0; nt < 4; ++nt) {                                                     \
            short8 bf = *(const short8*)(Act + swz(nt*16 + l15, k0));                        \
            acc[0][nt] = __builtin_amdgcn_mfma_f32_16x16x32_bf16(AF0, bf, acc[0][nt], 0,0,0);\
            acc[1][nt] = __builtin_amdgcn_mfma_f32_16x16x32_bf16(AF1, bf, acc[1][nt], 0,0,0);\
            acc[2][nt] = __builtin_amdgcn_mfma_f32_16x16x32_bf16(AF2, bf, acc[2][nt], 0,0,0);\
            acc[3][nt] = __builtin_amdgcn_mfma_f32_16x16x32_bf16(AF3, bf, acc[3][nt], 0,0,0);\
        }                                                                                    \
    }

#define KSLICE_BODY(WSRC, K0)                                                                \
    {                                                                                        \
        const unsigned short* Ar = (WSRC) + (g*64 + l15) * WPITCH + kg*8;                    \
        short8 af0 = *(const short8*)(Ar + 0*16*WPITCH);                                     \
        short8 af1 = *(const short8*)(Ar + 1*16*WPITCH);                                     \
        short8 af2 = *(const short8*)(Ar + 2*16*WPITCH);                                     \
        short8 af3 = *(const short8*)(Ar + 3*16*WPITCH);                                     \
        KSLICE_MFMA(af0, af1, af2, af3, K0)                                                  \
    }

// acc init = bias (MFMA C-in accumulates) — deletes the epilogue adds.
#define ACC_INIT_BIAS(BV)                                     \
    _Pragma("unroll")                                         \
    for (int mt = 0; mt < 4; ++mt)                            \
        _Pragma("unroll")                                     \
        for (int nt = 0; nt < 4; ++nt)                        \
            acc[mt][nt] = (BV)[mt];

// One expert per block: blockIdx = tile*8 + e (XCD round-robin -> blocks on an
// XCD share the expert; weights L2-resident). 4 waves, wave g owns neurons
// [g*64,+64) x ALL 64 points. LDS = Act only (aliased cbufK/pscr) = 32768 B.
// (256,4): unified cap 128 = 64 arch + 64 acc — demand is 68 arch, so the
// allocator shaves ~4 regs (R23's failure was demand 115; now it fits).
// Target: 4 waves/SIMD, 16 waves/CU — first real occupancy gain.
__global__ __launch_bounds__(NTHREADS, 4) void moe_expert(
    const float* __restrict__ coords, int npts,
    const unsigned short* __restrict__ W0k, const float* __restrict__ b1,
    const unsigned short* __restrict__ W1p,
    const unsigned short* __restrict__ W2p, const float* __restrict__ b2,
    const float* __restrict__ W3, const float* __restrict__ b3,
    float* __restrict__ ws)
{
    __shared__ __align__(16) unsigned short Act[NT * HD];      // 32 KB (ONLY buffer)
    unsigned short* cbufK = Act;        // alias: live phase 0-1 only
    float* pscr = (float*)Act;          // alias: live tail only

    const int t = threadIdx.x;
    const int lane = t & 63;
    const int g = t >> 6;       // 0..3: neuron group of 64
    const int l15 = lane & 15;
    const int kg = lane >> 4;
    const int e = blockIdx.x & 7;
    const int p0 = (blockIdx.x >> 3) * NT;

    const unsigned short* W0e = W0k + e * SLICE_ELEMS;
    const unsigned short* W1e = W1p + e * 8 * SLICE_ELEMS;
    const unsigned short* W2e = W2p + e * 8 * SLICE_ELEMS;

    // ---- pre-barrier loads: W0 af frags (hide L2 latency under barrier [1]) ----
    const unsigned short* Ar0 = W0e + (g*64 + l15) * WPITCH + kg*8;
    short8 paf0 = *(const short8*)(Ar0 + 0*16*WPITCH);
    short8 paf1 = *(const short8*)(Ar0 + 1*16*WPITCH);
    short8 paf2 = *(const short8*)(Ar0 + 2*16*WPITCH);
    short8 paf3 = *(const short8*)(Ar0 + 3*16*WPITCH);

    // ---- phase 0: build per-point L0 B-slots (hi/lo split) into cbufK ----
    if (t < NT) {
        int p = p0 + t;
        int pc = p < npts ? p : npts - 1;      // clamp; store masked later
        float x = coords[pc*3], y = coords[pc*3+1], z = coords[pc*3+2];
        unsigned short xh,xl,yh,yl,zh,zl;
        bfsplit(x,xh,xl); bfsplit(y,yh,yl); bfsplit(z,zh,zl);
        const unsigned short ONE = 0x3F80;     // bf16(1.0)
        union { unsigned short s[32]; uint4 q[4]; } pk;
        #pragma unroll
        for (int i = 0; i < 32; ++i) pk.s[i] = 0;
        pk.s[0]=xh; pk.s[1]=xl; pk.s[2]=xh;
        pk.s[3]=yh; pk.s[4]=yl; pk.s[5]=yh;
        pk.s[6]=zh; pk.s[7]=zl; pk.s[8]=zh;
        pk.s[9]=ONE; pk.s[10]=ONE;
        uint4* dst = (uint4*)(cbufK + t * 32);
        dst[0]=pk.q[0]; dst[1]=pk.q[1]; dst[2]=pk.q[2]; dst[3]=pk.q[3];
    }
    f32x4 b1v[4];
    #pragma unroll
    for (int mt = 0; mt < 4; ++mt)
        b1v[mt] = *(const f32x4*)(b1 + e*HD + g*64 + mt*16 + kg*4);
    __syncthreads();                    // [1] cbufK visible

    f32x4 acc[4][4];
    #pragma unroll
    for (int mt = 0; mt < 4; ++mt)
        #pragma unroll
        for (int nt = 0; nt < 4; ++nt)
            acc[mt][nt] = (f32x4){0.f, 0.f, 0.f, 0.f};

    // ---- phase 1: L0 as one MFMA K-slice (prefetched af, bias in slots) ----
    {
        #pragma unroll
        for (int nt = 0; nt < 4; ++nt) {
            short8 bf = *(const short8*)(cbufK + (nt*16 + l15) * 32 + kg*8);
            acc[0][nt] = __builtin_amdgcn_mfma_f32_16x16x32_bf16(paf0, bf, acc[0][nt], 0,0,0);
            acc[1][nt] = __builtin_amdgcn_mfma_f32_16x16x32_bf16(paf1, bf, acc[1][nt], 0,0,0);
            acc[2][nt] = __builtin_amdgcn_mfma_f32_16x16x32_bf16(paf2, bf, acc[2][nt], 0,0,0);
            acc[3][nt] = __builtin_amdgcn_mfma_f32_16x16x32_bf16(paf3, bf, acc[3][nt], 0,0,0);
        }
        // prefetch layer-1 slice 0 af (hides under barrier [1b] + epilogue)
        const unsigned short* Ar1 = W1e + (g*64 + l15) * WPITCH + kg*8;
        paf0 = *(const short8*)(Ar1 + 0*16*WPITCH);
        paf1 = *(const short8*)(Ar1 + 1*16*WPITCH);
        paf2 = *(const short8*)(Ar1 + 2*16*WPITCH);
        paf3 = *(const short8*)(Ar1 + 3*16*WPITCH);
    }
    __syncthreads();                    // [1b] all cbufK reads done (alias clobber)
    // ---- L0 epilogue: relu + pack -> Act (bias already in the MFMA slots) ----
    #pragma unroll
    for (int mt = 0; mt < 4; ++mt)
        #pragma unroll
        for (int nt = 0; nt < 4; ++nt) {
            const int p = nt*16 + l15;
            const int n0 = g*64 + mt*16 + kg*4;
            unsigned int lo = pack2bf(fmaxf(acc[mt][nt][0], 0.f),
                                      fmaxf(acc[mt][nt][1], 0.f));
            unsigned int hi = pack2bf(fmaxf(acc[mt][nt][2], 0.f),
                                      fmaxf(acc[mt][nt][3], 0.f));
            *(uint2*)(Act + swz(p, n0)) = make_uint2(lo, hi);
        }
    __syncthreads();                    // [2] Act W->R boundary

    ACC_INIT_BIAS(b1v)                  // bias pre-loaded into C
    // ---- layer 1: slice 0 from prefetched af, then 7 slices barrier-free ----
    KSLICE_MFMA(paf0, paf1, paf2, paf3, 0)
    #pragma unroll
    for (int s = 1; s < 8; ++s) {
        KSLICE_BODY(W1e + s * SLICE_ELEMS, s*32)
    }
    // prefetch layer-2 slice 0 af (hides under epilogue + barriers [3][4])
    {
        const unsigned short* Ar2 = W2e + (g*64 + l15) * WPITCH + kg*8;
        paf0 = *(const short8*)(Ar2 + 0*16*WPITCH);
        paf1 = *(const short8*)(Ar2 + 1*16*WPITCH);
        paf2 = *(const short8*)(Ar2 + 2*16*WPITCH);
        paf3 = *(const short8*)(Ar2 + 3*16*WPITCH);
    }
    __syncthreads();                    // [3] all Act reads done (R->W boundary)

    // ---- layer-1 epilogue: relu (bias already in acc) -> Act in place ----
    #pragma unroll
    for (int mt = 0; mt < 4; ++mt) {
        const int n0 = g*64 + mt*16 + kg*4;
        #pragma unroll
        for (int nt = 0; nt < 4; ++nt) {
            const int p = nt*16 + l15;
            unsigned int lo = pack2bf(fmaxf(acc[mt][nt][0], 0.f),
                                      fmaxf(acc[mt][nt][1], 0.f));
            unsigned int hi = pack2bf(fmaxf(acc[mt][nt][2], 0.f),
                                      fmaxf(acc[mt][nt][3], 0.f));
            *(uint2*)(Act + swz(p, n0)) = make_uint2(lo, hi);
        }
    }
    f32x4 b2v[4], w3v[4];
    #pragma unroll
    for (int mt = 0; mt < 4; ++mt) {
        const int nb = g*64 + mt*16 + kg*4;
        b2v[mt] = *(const f32x4*)(b2 + e*HD + nb);
        w3v[mt] = *(const f32x4*)(W3 + e*HD + nb);
    }
    __syncthreads();                    // [4] Act W->R boundary

    ACC_INIT_BIAS(b2v)                  // bias pre-loaded into C
    // ---- layer 2: slice 0 from prefetched af, then 7 slices barrier-free ----
    KSLICE_MFMA(paf0, paf1, paf2, paf3, 0)
    #pragma unroll
    for (int s = 1; s < 8; ++s) {
        KSLICE_BODY(W2e + s * SLICE_ELEMS, s*32)
    }
    __syncthreads();                    // [4b] all Act reads done (pscr alias safe)

    // ---- fused layer-2 epilogue + layer 3 (fp32, in registers) ----
    #pragma unroll
    for (int nt = 0; nt < 4; ++nt) {
        float s = 0.f;
        #pragma unroll
        for (int mt = 0; mt < 4; ++mt)
            #pragma unroll
            for (int r = 0; r < 4; ++r)
                s += fmaxf(acc[mt][nt][r], 0.f) * w3v[mt][r];
        s += __shfl_xor(s, 16);   // reduce over kg (4 lanes per point)
        s += __shfl_xor(s, 32);
        if (kg == 0) pscr[(nt*16 + l15) * 4 + g] = s;   // pscr aliases Act
    }
    __syncthreads();                    // [5] pscr W->R boundary
    if (t < NT) {
        f32x4 v = *(const f32x4*)(pscr + t * 4);
        int p = p0 + t;
        if (p < npts) ws[e * npts + p] = v[0] + v[1] + v[2] + v[3] + b3[e];
    }
}

// Max over the 8 experts' partials.
__global__ void moe_reduce(const float* __restrict__ ws, float* __restrict__ out, int npts) {
    int p = blockIdx.x * 256 + threadIdx.x;
    if (p >= npts) return;
    float m = ws[p];
    #pragma unroll
    for (int e = 1; e < NE; ++e) m = fmaxf(m, ws[e * npts + p]);
    out[p] = m;
}

extern "C" void kernel_launch(void* const* d_in, const int* in_sizes, int n_in,
                              void* d_out, int out_size, void* d_ws, size_t ws_size,
                              hipStream_t stream) {
    const float* coords = (const float*)d_in[0];
    const float* W0 = (const float*)d_in[1];
    const float* b0 = (const float*)d_in[2];
    const float* W1 = (const float*)d_in[3];
    const float* b1 = (const float*)d_in[4];
    const float* W2 = (const float*)d_in[5];
    const float* b2 = (const float*)d_in[6];
    const float* W3 = (const float*)d_in[7];
    const float* b3 = (const float*)d_in[8];
    const int npts = in_sizes[0] / 3;

    unsigned short* W1p = (unsigned short*)d_ws;                   // 1 MB
    unsigned short* W2p = W1p + NE * 8 * SLICE_ELEMS;              // 1 MB
    unsigned short* W0k = W2p + NE * 8 * SLICE_ELEMS;              // 128 KB
    float* eout = (float*)(W0k + NE * SLICE_ELEMS);                // 3.2 MB

    const int PREP_TOT = NE * 8 * SLICE_ELEMS;
    prep_weights<<<(PREP_TOT + 255) / 256, 256, 0, stream>>>(W1, W2, W1p, W2p);
    prep_w0<<<(NE * HD + 255) / 256, 256, 0, stream>>>(W0, b0, W0k);

    int ntiles = (npts + NT - 1) / NT;
    moe_expert<<<ntiles * NE, NTHREADS, 0, stream>>>(
        coords, npts, W0k, b1, W1p, W2p, b2, W3, b3, eout);

    moe_reduce<<<(npts + 255) / 256, 256, 0, stream>>>(eout, (float*)d_out, npts);
}